// Round 1
// baseline (382.117 us; speedup 1.0000x reference)
//
#include <hip/hip_runtime.h>

// Tree-mux reduction, coalesced formulation, single fused kernel.
// root = sum_i x[i] * prod_l c(l, bit_l(i)), c(l,0)=0.5(1+w[l]), c(l,1)=0.5(1-w[l]).
// Leaf 2^25-1 is virtual = trained_const_weight.
//
// Grid 4096 x 256. Block covers 8192 leaves. Element index
// e = blk*8192 + iter*1024 + tid*4 -> lane-consecutive float4 (coalesced).
// float4 collapses levels 0..1; iter bits -> levels 10..12 (weighted acc);
// lane bits -> levels 2..7 (butterfly); wave bits -> levels 8..9 (LDS).
// Last-finishing block (device-scope counter in ws, zeroed by a 4B
// hipMemsetAsync captured in the graph) performs the exact level-13..24
// tree over the 4096 partials -- bit-identical to the old separate k2,
// but saves one kernel dispatch + inter-kernel gap.
#define NBLK 4096

__global__ __launch_bounds__(256) void k1(const float* __restrict__ x,
                                          const float* __restrict__ cw,
                                          const float* __restrict__ w,
                                          float* __restrict__ part,
                                          unsigned* __restrict__ counter,
                                          float* __restrict__ out) {
    float cA[13], cB[13];
#pragma unroll
    for (int l = 0; l < 13; ++l) {
        float s = w[l];
        cA[l] = 0.5f * (1.0f + s);
        cB[l] = 0.5f * (1.0f - s);
    }
    // iteration coefficients: iter bit k <-> global level 10+k
    float ic[8];
#pragma unroll
    for (int i = 0; i < 8; ++i) {
        float c = ((i & 1) ? cB[10] : cA[10]);
        c *= ((i & 2) ? cB[11] : cA[11]);
        c *= ((i & 4) ? cB[12] : cA[12]);
        ic[i] = c;
    }
    const int t = threadIdx.x;
    const int b = blockIdx.x;
    const int blockBase = b * 8192;
    float acc = 0.0f;

#pragma unroll
    for (int it = 0; it < 8; ++it) {
        const int e = blockBase + it * 1024 + t * 4;
        float fx, fy, fz, fw;
        if (it == 7 && b == NBLK - 1) {          // uniform branch (compile-time it)
            if (t == 255) {                       // owns leaves 2^25-4 .. 2^25-1
                fx = x[e]; fy = x[e + 1]; fz = x[e + 2]; fw = cw[0];
            } else {
                float4 f = *reinterpret_cast<const float4*>(x + e);
                fx = f.x; fy = f.y; fz = f.z; fw = f.w;
            }
        } else {
            float4 f = *reinterpret_cast<const float4*>(x + e);
            fx = f.x; fy = f.y; fz = f.z; fw = f.w;
        }
        float p = cA[1] * (cA[0] * fx + cB[0] * fy) +
                  cB[1] * (cA[0] * fz + cB[0] * fw);
        acc = fmaf(ic[it], p, acc);
    }

    // butterfly shuffle: lane bit k <-> global level 2+k
    float val = acc;
#pragma unroll
    for (int k = 0; k < 6; ++k) {
        const int l = 2 + k;
        float other = __shfl_xor(val, 1 << k, 64);
        bool upper = (t >> k) & 1;
        float a = upper ? other : val;
        float bb = upper ? val : other;
        val = cA[l] * a + cB[l] * bb;
    }

    // wave bits: tid bit6 <-> level 8, bit7 <-> level 9
    __shared__ float lds[4];
    __shared__ int lastFlag;
    if ((t & 63) == 0) lds[t >> 6] = val;
    __syncthreads();
    if (t == 0) {
        float p01 = cA[8] * lds[0] + cB[8] * lds[1];
        float p23 = cA[8] * lds[2] + cB[8] * lds[3];
        part[b] = cA[9] * p01 + cB[9] * p23;
        __threadfence();                          // release part[b] (device scope, cross-XCD)
        unsigned old = atomicAdd(counter, 1u);
        lastFlag = (old == NBLK - 1) ? 1 : 0;
    }
    __syncthreads();
    if (!lastFlag) return;                        // block-uniform exit

    // ---- winner block only: levels 13..24 over part[0..4095] (== old k2) ----
    __threadfence();                              // acquire all blocks' part writes
    float dA[12], dB[12];
#pragma unroll
    for (int l = 0; l < 12; ++l) {
        float s = w[13 + l];
        dA[l] = 0.5f * (1.0f + s);
        dB[l] = 0.5f * (1.0f - s);
    }
    float v[16];
#pragma unroll
    for (int j = 0; j < 4; ++j) {
        float4 f = *reinterpret_cast<const float4*>(part + t * 16 + j * 4);
        v[4 * j + 0] = f.x; v[4 * j + 1] = f.y;
        v[4 * j + 2] = f.z; v[4 * j + 3] = f.w;
    }
#pragma unroll
    for (int l = 0, n = 16; n > 1; n >>= 1, ++l) {
#pragma unroll
        for (int i = 0; i < n / 2; ++i)
            v[i] = dA[l] * v[2 * i] + dB[l] * v[2 * i + 1];
    }
    float fv = v[0];
#pragma unroll
    for (int k = 0; k < 6; ++k) {
        const int l = 4 + k;                      // global level 17..22
        float other = __shfl_xor(fv, 1 << k, 64);
        bool upper = (t >> k) & 1;
        float a = upper ? other : fv;
        float bb = upper ? fv : other;
        fv = dA[l] * a + dB[l] * bb;
    }
    __syncthreads();                              // reuse lds[] safely
    if ((t & 63) == 0) lds[t >> 6] = fv;
    __syncthreads();
    if (t == 0) {
        float p01 = dA[10] * lds[0] + dB[10] * lds[1];  // level 23
        float p23 = dA[10] * lds[2] + dB[10] * lds[3];
        out[0] = dA[11] * p01 + dB[11] * p23;           // level 24
    }
}

extern "C" void kernel_launch(void* const* d_in, const int* in_sizes, int n_in,
                              void* d_out, int out_size, void* d_ws, size_t ws_size,
                              hipStream_t stream) {
    const float* x  = (const float*)d_in[0];   // 2^25-1 floats
    const float* cw = (const float*)d_in[1];   // 1 float
    const float* w  = (const float*)d_in[2];   // 25 floats
    float* part = (float*)d_ws;                // 4096 floats = 16 KiB scratch
    unsigned* counter = (unsigned*)((char*)d_ws + NBLK * sizeof(float));

    hipMemsetAsync(counter, 0, sizeof(unsigned), stream);  // graph-capturable
    k1<<<NBLK, 256, 0, stream>>>(x, cw, w, part, counter, (float*)d_out);
}

// Round 2
// 190.487 us; speedup vs baseline: 2.0060x; 2.0060x over previous
//
#include <hip/hip_runtime.h>

// Tree-mux reduction, coalesced formulation.
// root = sum_i x[i] * prod_l c(l, bit_l(i)), c(l,0)=0.5(1+w[l]), c(l,1)=0.5(1-w[l]).
// Leaf 2^25-1 is virtual = trained_const_weight.
//
// k1: grid 4096 x 256. Block covers 8192 leaves. Element index
// e = blk*8192 + iter*1024 + tid*4 -> lane-consecutive float4 (coalesced).
// float4 collapses levels 0..1; iter bits (of the level-2 node index) are
// levels 10..12 -> weighted accumulate; lane bits -> levels 2..7 (butterfly);
// wave bits -> levels 8..9 (LDS). One partial per block.
//
// NOTE (round 1 post-mortem): fusing k2 via last-block-done (threadfence +
// single atomic counter) regressed 190->382 us: 4096 serialized device-scope
// RMWs on one cache line across 8 XCDs cost ~170 us (k1 241 us, VALUBusy 2%,
// 274 GB/s). The separate 1-block k2 dispatch (~2 us) is the cheap option.
__global__ __launch_bounds__(256) void k1(const float* __restrict__ x,
                                          const float* __restrict__ cw,
                                          const float* __restrict__ w,
                                          float* __restrict__ part) {
    float cA[13], cB[13];
#pragma unroll
    for (int l = 0; l < 13; ++l) {
        float s = w[l];
        cA[l] = 0.5f * (1.0f + s);
        cB[l] = 0.5f * (1.0f - s);
    }
    // iteration coefficients: iter bit k <-> global level 10+k
    float ic[8];
#pragma unroll
    for (int i = 0; i < 8; ++i) {
        float c = ((i & 1) ? cB[10] : cA[10]);
        c *= ((i & 2) ? cB[11] : cA[11]);
        c *= ((i & 4) ? cB[12] : cA[12]);
        ic[i] = c;
    }
    const int t = threadIdx.x;
    const int b = blockIdx.x;
    const int blockBase = b * 8192;
    float acc = 0.0f;

#pragma unroll
    for (int it = 0; it < 8; ++it) {
        const int e = blockBase + it * 1024 + t * 4;
        float fx, fy, fz, fw;
        if (it == 7 && b == 4095) {              // uniform branch (compile-time it)
            if (t == 255) {                       // owns leaves 2^25-4 .. 2^25-1
                fx = x[e]; fy = x[e + 1]; fz = x[e + 2]; fw = cw[0];
            } else {
                float4 f = *reinterpret_cast<const float4*>(x + e);
                fx = f.x; fy = f.y; fz = f.z; fw = f.w;
            }
        } else {
            float4 f = *reinterpret_cast<const float4*>(x + e);
            fx = f.x; fy = f.y; fz = f.z; fw = f.w;
        }
        float p = cA[1] * (cA[0] * fx + cB[0] * fy) +
                  cB[1] * (cA[0] * fz + cB[0] * fw);
        acc = fmaf(ic[it], p, acc);
    }

    // butterfly shuffle: lane bit k <-> global level 2+k
    float val = acc;
#pragma unroll
    for (int k = 0; k < 6; ++k) {
        const int l = 2 + k;
        float other = __shfl_xor(val, 1 << k, 64);
        bool upper = (t >> k) & 1;
        float a = upper ? other : val;
        float bb = upper ? val : other;
        val = cA[l] * a + cB[l] * bb;
    }

    // wave bits: tid bit6 <-> level 8, bit7 <-> level 9
    __shared__ float lds[4];
    if ((t & 63) == 0) lds[t >> 6] = val;
    __syncthreads();
    if (t == 0) {
        float p01 = cA[8] * lds[0] + cB[8] * lds[1];
        float p23 = cA[8] * lds[2] + cB[8] * lds[3];
        part[b] = cA[9] * p01 + cB[9] * p23;
    }
}

// k2: 1 block x 256 threads over 4096 partials (levels 13..24), exact tree.
__global__ __launch_bounds__(256) void k2(const float* __restrict__ part,
                                          const float* __restrict__ w,
                                          float* __restrict__ out) {
    float cA[12], cB[12];
#pragma unroll
    for (int l = 0; l < 12; ++l) {
        float s = w[13 + l];
        cA[l] = 0.5f * (1.0f + s);
        cB[l] = 0.5f * (1.0f - s);
    }
    const int t = threadIdx.x;
    float v[16];
#pragma unroll
    for (int j = 0; j < 4; ++j) {
        float4 f = *reinterpret_cast<const float4*>(part + t * 16 + j * 4);
        v[4 * j + 0] = f.x; v[4 * j + 1] = f.y;
        v[4 * j + 2] = f.z; v[4 * j + 3] = f.w;
    }
#pragma unroll
    for (int l = 0, n = 16; n > 1; n >>= 1, ++l) {
#pragma unroll
        for (int i = 0; i < n / 2; ++i)
            v[i] = cA[l] * v[2 * i] + cB[l] * v[2 * i + 1];
    }
    float val = v[0];
#pragma unroll
    for (int k = 0; k < 6; ++k) {
        const int l = 4 + k;  // global level 17..22
        float other = __shfl_xor(val, 1 << k, 64);
        bool upper = (t >> k) & 1;
        float a = upper ? other : val;
        float bb = upper ? val : other;
        val = cA[l] * a + cB[l] * bb;
    }
    __shared__ float lds[4];
    if ((t & 63) == 0) lds[t >> 6] = val;
    __syncthreads();
    if (t == 0) {
        float p01 = cA[10] * lds[0] + cB[10] * lds[1];  // level 23
        float p23 = cA[10] * lds[2] + cB[10] * lds[3];
        out[0] = cA[11] * p01 + cB[11] * p23;           // level 24
    }
}

extern "C" void kernel_launch(void* const* d_in, const int* in_sizes, int n_in,
                              void* d_out, int out_size, void* d_ws, size_t ws_size,
                              hipStream_t stream) {
    const float* x  = (const float*)d_in[0];  // 2^25-1 floats
    const float* cw = (const float*)d_in[1];  // 1 float
    const float* w  = (const float*)d_in[2];  // 25 floats
    float* part = (float*)d_ws;               // 4096 floats = 16 KiB scratch

    k1<<<4096, 256, 0, stream>>>(x, cw, w, part);
    k2<<<1, 256, 0, stream>>>(part, w, (float*)d_out);
}